// Round 2
// baseline (1731.144 us; speedup 1.0000x reference)
//
#include <hip/hip_runtime.h>
#include <cstdint>
#include <cstddef>

typedef unsigned short u16;
typedef short bf16x8 __attribute__((ext_vector_type(8)));
typedef float f32x4 __attribute__((ext_vector_type(4)));

#define HIDDEN 4096
#define NH 32
#define NKV 8
#define HD 128
#define SEQL 2048
#define BATCH 2
#define NTOK (BATCH*SEQL)          /* 4096 tokens */
#define QKVN (HIDDEN + 2*NKV*HD)   /* 6144 */

__device__ __forceinline__ u16 f2bf(float f){
    unsigned u = __float_as_uint(f);
    u += 0x7FFF + ((u >> 16) & 1);   // RNE
    return (u16)(u >> 16);
}
__device__ __forceinline__ float bf2f(u16 h){
    return __uint_as_float(((unsigned)h) << 16);
}
__device__ __forceinline__ f32x4 zero4(){
    f32x4 z; z[0]=0.f; z[1]=0.f; z[2]=0.f; z[3]=0.f; return z;
}

typedef const unsigned int __attribute__((address_space(1)))* gas1_t;
typedef unsigned int __attribute__((address_space(3)))* las3_t;
__device__ __forceinline__ void gload_lds16(const u16* g, u16* l){
    __builtin_amdgcn_global_load_lds((gas1_t)g, (las3_t)l, 16, 0, 0);
}

// ---------------- f32 -> bf16 conversion (vectorized x4) ----------------
__global__ __launch_bounds__(256) void cvt_kernel(const float* __restrict__ src,
                                                  u16* __restrict__ dst, int n4){
    int i = blockIdx.x * 256 + threadIdx.x;
    if (i < n4){
        float4 v = ((const float4*)src)[i];
        ushort4 o;
        o.x = f2bf(v.x); o.y = f2bf(v.y); o.z = f2bf(v.z); o.w = f2bf(v.w);
        ((ushort4*)dst)[i] = o;
    }
}

// ---------------- GEMM: C[m,n] = sum_k A[m,k]*B[n,k], A,B bf16 K-contig ----------------
// 128x128 tile, BK=32, 256 threads (4 waves, 2x2 of 64x64), global_load_lds width 16.
template<int OUT_BF16>
__global__ __launch_bounds__(256) void gemm_bt(const u16* __restrict__ A,
                                               const u16* __restrict__ B,
                                               void* __restrict__ Cp,
                                               int M, int N, int K){
    __shared__ __align__(16) u16 As[128*32];
    __shared__ __align__(16) u16 Bs[128*32];
    int tid = threadIdx.x;
    int wave = tid >> 6, lane = tid & 63, quad = lane >> 4, l16 = lane & 15;
    int wm = wave & 1, wn = wave >> 1;
    size_t row0 = (size_t)blockIdx.y * 128, col0 = (size_t)blockIdx.x * 128;

    f32x4 acc[4][4];
    #pragma unroll
    for (int i=0;i<4;i++)
        #pragma unroll
        for (int j=0;j<4;j++) acc[i][j] = zero4();

    const u16* Ag = A + (row0 + (tid >> 2)) * (size_t)K + (tid & 3) * 8;
    const u16* Bg = B + (col0 + (tid >> 2)) * (size_t)K + (tid & 3) * 8;
    u16* Asp = As + tid * 8;
    u16* Bsp = Bs + tid * 8;
    size_t skip = (size_t)64 * K;

    for (int k0 = 0; k0 < K; k0 += 32){
        gload_lds16(Ag + k0,        Asp);
        gload_lds16(Ag + k0 + skip, Asp + 2048);
        gload_lds16(Bg + k0,        Bsp);
        gload_lds16(Bg + k0 + skip, Bsp + 2048);
        __syncthreads();
        bf16x8 af[4], bfr[4];
        #pragma unroll
        for (int i=0;i<4;i++) af[i]  = *(const bf16x8*)(As + (wm*64 + i*16 + l16)*32 + quad*8);
        #pragma unroll
        for (int j=0;j<4;j++) bfr[j] = *(const bf16x8*)(Bs + (wn*64 + j*16 + l16)*32 + quad*8);
        #pragma unroll
        for (int i=0;i<4;i++)
            #pragma unroll
            for (int j=0;j<4;j++)
                acc[i][j] = __builtin_amdgcn_mfma_f32_16x16x32_bf16(af[i], bfr[j], acc[i][j], 0, 0, 0);
        __syncthreads();
    }

    // epilogue: C row = row0+wm*64+i*16+quad*4+r, col = col0+wn*64+j*16+l16
    #pragma unroll
    for (int i=0;i<4;i++)
        #pragma unroll
        for (int j=0;j<4;j++){
            size_t row = row0 + wm*64 + i*16 + quad*4;
            size_t col = col0 + wn*64 + j*16 + l16;
            #pragma unroll
            for (int r=0;r<4;r++){
                if (OUT_BF16) ((u16*)Cp)[(row + r) * (size_t)N + col] = f2bf(acc[i][j][r]);
                else          ((float*)Cp)[(row + r) * (size_t)N + col] = acc[i][j][r];
            }
        }
}

// ---------------- RoPE (in-place on QKV) + V transpose ----------------
__global__ __launch_bounds__(256) void rope_kernel(u16* __restrict__ qkv,
                                                   const int* __restrict__ pos_ids,
                                                   u16* __restrict__ Vt){
    int idx = blockIdx.x * 256 + threadIdx.x;
    if (idx < 8388608){
        int tok = idx >> 11;          // / (32*64)
        int rem = idx & 2047;
        int h = rem >> 6, d = rem & 63;
        size_t base = (size_t)tok * QKVN + h * 128 + d;
        float v1 = bf2f(qkv[base]), v2 = bf2f(qkv[base + 64]);
        float p = (float)pos_ids[tok];
        float invf = exp2f((float)d * -0.2076205059304601f);  // 10000^(-d/64)
        float fr = p * invf;
        float s, c; sincosf(fr, &s, &c);
        qkv[base]      = f2bf(v1 * c - v2 * s);
        qkv[base + 64] = f2bf(v2 * c + v1 * s);
    } else if (idx < 10485760){
        int i2 = idx - 8388608;
        int tok = i2 >> 9;            // / (8*64)
        int rem = i2 & 511;
        int kv = rem >> 6, d = rem & 63;
        size_t base = (size_t)tok * QKVN + HIDDEN + kv * 128 + d;
        float v1 = bf2f(qkv[base]), v2 = bf2f(qkv[base + 64]);
        float p = (float)pos_ids[tok];
        float invf = exp2f((float)d * -0.2076205059304601f);
        float fr = p * invf;
        float s, c; sincosf(fr, &s, &c);
        qkv[base]      = f2bf(v1 * c - v2 * s);
        qkv[base + 64] = f2bf(v2 * c + v1 * s);
    } else if (idx < 14680064){
        int i3 = idx - 10485760;
        int tok = i3 >> 10;           // / (8*128)
        int rem = i3 & 1023;
        int kv = rem >> 7, d = rem & 127;
        int b = tok >> 11, s = tok & 2047;
        Vt[(((size_t)(b * NKV + kv)) * HD + d) * SEQL + s] =
            qkv[(size_t)tok * QKVN + 5120 + kv * 128 + d];
    }
}

// ---------------- Flash attention v2: barrier-free, register-direct ----------------
// One block = (b, h, 64-row q tile); each wave owns 16 q rows independently.
// All MFMA operands loaded straight from global (K-contiguous); LDS only for
// the per-wave P C-layout -> A-layout transform (no __syncthreads anywhere).
__global__ __launch_bounds__(256) void attn_kernel(const u16* __restrict__ qkv,
                                                   const u16* __restrict__ Vt,
                                                   u16* __restrict__ outb){
    __shared__ __align__(16) u16 Ps[4][16*136];   // stride 136 u16: 16B-aligned rows, no pow2 bank alias

    int qt = blockIdx.x & 31;
    int h  = (blockIdx.x >> 5) & 31;
    int b  = blockIdx.x >> 10;
    int kvh = h >> 2;
    int tid = threadIdx.x, wave = tid >> 6, lane = tid & 63;
    int quad = lane >> 4, l16 = lane & 15;
    int q0 = qt * 64;
    int qrow = q0 + wave * 16;          // this wave's base q row

    const u16* Qg    = qkv + (size_t)(b * SEQL + qrow + l16) * QKVN + h * HD;
    const u16* Kbase = qkv + (size_t)(b * SEQL) * QKVN + HIDDEN + kvh * HD;
    const u16* Vg    = Vt + ((size_t)(b * NKV + kvh)) * HD * SEQL;
    u16* Pw = &Ps[wave][0];

    // Q fragments for this wave's 16 rows, resident in registers for the whole k-loop
    bf16x8 qf[4];
    #pragma unroll
    for (int c = 0; c < 4; c++) qf[c] = *(const bf16x8*)(Qg + c * 32 + quad * 8);

    float m_i[4] = {-INFINITY, -INFINITY, -INFINITY, -INFINITY};
    float l_i[4] = {0.f, 0.f, 0.f, 0.f};
    f32x4 Oacc[8];
    #pragma unroll
    for (int t=0;t<8;t++) Oacc[t] = zero4();

    const float scale = 0.08838834764831845f;  // 1/sqrt(128)
    int kend = qrow + 16;                      // per-wave causal bound
    for (int k0 = 0; k0 < kend; k0 += 128){
        // ---- S = Q K^T for 16 rows x 128 keys, operands direct from global ----
        f32x4 st[8];
        #pragma unroll
        for (int t=0;t<8;t++) st[t] = zero4();
        #pragma unroll
        for (int c = 0; c < 4; c++){
            #pragma unroll
            for (int t = 0; t < 8; t++){
                bf16x8 bk = *(const bf16x8*)(Kbase + (size_t)(k0 + t*16 + l16) * QKVN + c*32 + quad*8);
                st[t] = __builtin_amdgcn_mfma_f32_16x16x32_bf16(qf[c], bk, st[t], 0, 0, 0);
            }
        }

        // ---- online softmax (C layout: row = quad*4+r, col = t*16+l16) ----
        bool needmask = (k0 + 127 > qrow);     // wave-uniform
        int row_g = qrow + quad * 4;
        float alpha[4];
        #pragma unroll
        for (int r=0;r<4;r++){
            float mx = m_i[r];
            #pragma unroll
            for (int t=0;t<8;t++){
                float v = st[t][r] * scale;
                if (needmask){
                    int col = k0 + t*16 + l16;
                    v = (col <= row_g + r) ? v : -INFINITY;
                }
                st[t][r] = v;
                mx = fmaxf(mx, v);
            }
            #pragma unroll
            for (int m=8;m>=1;m>>=1) mx = fmaxf(mx, __shfl_xor(mx, m));
            float mnew = mx;
            alpha[r] = __expf(m_i[r] - mnew);
            float rs = 0.f;
            #pragma unroll
            for (int t=0;t<8;t++){
                float pv = __expf(st[t][r] - mnew);
                st[t][r] = pv;
                rs += pv;
            }
            #pragma unroll
            for (int m=8;m>=1;m>>=1) rs += __shfl_xor(rs, m);
            l_i[r] = l_i[r] * alpha[r] + rs;
            m_i[r] = mnew;
        }

        // rescale O
        #pragma unroll
        for (int t=0;t<8;t++)
            #pragma unroll
            for (int r=0;r<4;r++) Oacc[t][r] *= alpha[r];

        // ---- P: C-layout -> per-wave LDS -> A-layout (no barrier: wave-private) ----
        #pragma unroll
        for (int t=0;t<8;t++)
            #pragma unroll
            for (int r=0;r<4;r++)
                Pw[(quad*4 + r)*136 + t*16 + l16] = f2bf(st[t][r]);

        // ---- O += P(16x128) @ V(128x128); Vt rows are key-contiguous ----
        #pragma unroll
        for (int c = 0; c < 4; c++){
            bf16x8 ap = *(const bf16x8*)(Pw + l16*136 + c*32 + quad*8);
            #pragma unroll
            for (int t = 0; t < 8; t++){
                bf16x8 bv = *(const bf16x8*)(Vg + (size_t)(t*16 + l16) * SEQL + k0 + c*32 + quad*8);
                Oacc[t] = __builtin_amdgcn_mfma_f32_16x16x32_bf16(ap, bv, Oacc[t], 0, 0, 0);
            }
        }
    }

    float invl[4];
    #pragma unroll
    for (int r=0;r<4;r++) invl[r] = 1.f / l_i[r];
    int row0 = qrow + quad * 4;
    #pragma unroll
    for (int t=0;t<8;t++)
        #pragma unroll
        for (int r=0;r<4;r++){
            size_t o = ((size_t)(b * SEQL + row0 + r)) * HIDDEN + h * HD + t*16 + l16;
            outb[o] = f2bf(Oacc[t][r] * invl[r]);
        }
}

extern "C" void kernel_launch(void* const* d_in, const int* in_sizes, int n_in,
                              void* d_out, int out_size, void* d_ws, size_t ws_size,
                              hipStream_t stream){
    (void)in_sizes; (void)n_in; (void)out_size; (void)ws_size;
    const float* hs  = (const float*)d_in[0];
    const int*   pos = (const int*)d_in[1];
    const float* Wq  = (const float*)d_in[2];
    const float* Wk  = (const float*)d_in[3];
    const float* Wv  = (const float*)d_in[4];
    const float* Wo  = (const float*)d_in[5];
    float* out = (float*)d_out;
    char* ws = (char*)d_ws;

    // workspace layout (bytes)
    u16* Xbf  = (u16*)(ws);              // 4096x4096 bf16 (33.5MB) ; later reused as attn output
    u16* Wqkv = (u16*)(ws + 33554432);   // 6144x4096 bf16 (50.3MB)
    u16* Wob  = (u16*)(ws + 83886080);   // 4096x4096 bf16 (33.5MB)
    u16* QKVb = (u16*)(ws + 117440512);  // 4096x6144 bf16 (50.3MB)
    u16* Vt   = (u16*)(ws + 167772160);  // [2][8][128][2048] bf16 (8.4MB)
    u16* attn_bf = Xbf;                  // alias: X dead after QKV GEMM

    cvt_kernel<<<16384, 256, 0, stream>>>(hs, Xbf, 4194304);
    cvt_kernel<<<16384, 256, 0, stream>>>(Wq, Wqkv, 4194304);
    cvt_kernel<<<4096,  256, 0, stream>>>(Wk, Wqkv + (size_t)4096*4096, 1048576);
    cvt_kernel<<<4096,  256, 0, stream>>>(Wv, Wqkv + (size_t)5120*4096, 1048576);
    cvt_kernel<<<16384, 256, 0, stream>>>(Wo, Wob, 4194304);

    gemm_bt<1><<<dim3(48, 32), 256, 0, stream>>>(Xbf, Wqkv, QKVb, NTOK, QKVN, HIDDEN);
    rope_kernel<<<57344, 256, 0, stream>>>(QKVb, pos, Vt);
    attn_kernel<<<BATCH*NH*(SEQL/64), 256, 0, stream>>>(QKVb, Vt, attn_bf);
    gemm_bt<0><<<dim3(32, 32), 256, 0, stream>>>(attn_bf, Wob, out, NTOK, HIDDEN, HIDDEN);
}

// Round 3
// 1038.942 us; speedup vs baseline: 1.6663x; 1.6663x over previous
//
#include <hip/hip_runtime.h>
#include <cstdint>
#include <cstddef>

typedef unsigned short u16;
typedef short bf16x8 __attribute__((ext_vector_type(8)));
typedef float f32x4 __attribute__((ext_vector_type(4)));

#define HIDDEN 4096
#define NH 32
#define NKV 8
#define HD 128
#define SEQL 2048
#define BATCH 2
#define NTOK (BATCH*SEQL)          /* 4096 tokens */
#define QKVN (HIDDEN + 2*NKV*HD)   /* 6144 */

#define QKS 136   /* padded LDS row stride (u16) for Qs/Ks/Ps: 68 dwords = 4 mod 32 */
#define VSS 72    /* padded LDS row stride (u16) for Vs: 36 dwords = 4 mod 32 */

__device__ __forceinline__ u16 f2bf(float f){
    unsigned u = __float_as_uint(f);
    u += 0x7FFF + ((u >> 16) & 1);   // RNE
    return (u16)(u >> 16);
}
__device__ __forceinline__ float bf2f(u16 h){
    return __uint_as_float(((unsigned)h) << 16);
}
__device__ __forceinline__ f32x4 zero4(){
    f32x4 z; z[0]=0.f; z[1]=0.f; z[2]=0.f; z[3]=0.f; return z;
}

typedef const unsigned int __attribute__((address_space(1)))* gas1_t;
typedef unsigned int __attribute__((address_space(3)))* las3_t;
__device__ __forceinline__ void gload_lds16(const u16* g, u16* l){
    __builtin_amdgcn_global_load_lds((gas1_t)g, (las3_t)l, 16, 0, 0);
}

// ---------------- f32 -> bf16 conversion (vectorized x4) ----------------
__global__ __launch_bounds__(256) void cvt_kernel(const float* __restrict__ src,
                                                  u16* __restrict__ dst, int n4){
    int i = blockIdx.x * 256 + threadIdx.x;
    if (i < n4){
        float4 v = ((const float4*)src)[i];
        ushort4 o;
        o.x = f2bf(v.x); o.y = f2bf(v.y); o.z = f2bf(v.z); o.w = f2bf(v.w);
        ((ushort4*)dst)[i] = o;
    }
}

// ---------------- GEMM: C[m,n] = sum_k A[m,k]*B[n,k], A,B bf16 K-contig ----------------
template<int OUT_BF16>
__global__ __launch_bounds__(256) void gemm_bt(const u16* __restrict__ A,
                                               const u16* __restrict__ B,
                                               void* __restrict__ Cp,
                                               int M, int N, int K){
    __shared__ __align__(16) u16 As[128*32];
    __shared__ __align__(16) u16 Bs[128*32];
    int tid = threadIdx.x;
    int wave = tid >> 6, lane = tid & 63, quad = lane >> 4, l16 = lane & 15;
    int wm = wave & 1, wn = wave >> 1;
    size_t row0 = (size_t)blockIdx.y * 128, col0 = (size_t)blockIdx.x * 128;

    f32x4 acc[4][4];
    #pragma unroll
    for (int i=0;i<4;i++)
        #pragma unroll
        for (int j=0;j<4;j++) acc[i][j] = zero4();

    const u16* Ag = A + (row0 + (tid >> 2)) * (size_t)K + (tid & 3) * 8;
    const u16* Bg = B + (col0 + (tid >> 2)) * (size_t)K + (tid & 3) * 8;
    u16* Asp = As + tid * 8;
    u16* Bsp = Bs + tid * 8;
    size_t skip = (size_t)64 * K;

    for (int k0 = 0; k0 < K; k0 += 32){
        gload_lds16(Ag + k0,        Asp);
        gload_lds16(Ag + k0 + skip, Asp + 2048);
        gload_lds16(Bg + k0,        Bsp);
        gload_lds16(Bg + k0 + skip, Bsp + 2048);
        __syncthreads();
        bf16x8 af[4], bfr[4];
        #pragma unroll
        for (int i=0;i<4;i++) af[i]  = *(const bf16x8*)(As + (wm*64 + i*16 + l16)*32 + quad*8);
        #pragma unroll
        for (int j=0;j<4;j++) bfr[j] = *(const bf16x8*)(Bs + (wn*64 + j*16 + l16)*32 + quad*8);
        #pragma unroll
        for (int i=0;i<4;i++)
            #pragma unroll
            for (int j=0;j<4;j++)
                acc[i][j] = __builtin_amdgcn_mfma_f32_16x16x32_bf16(af[i], bfr[j], acc[i][j], 0, 0, 0);
        __syncthreads();
    }

    #pragma unroll
    for (int i=0;i<4;i++)
        #pragma unroll
        for (int j=0;j<4;j++){
            size_t row = row0 + wm*64 + i*16 + quad*4;
            size_t col = col0 + wn*64 + j*16 + l16;
            #pragma unroll
            for (int r=0;r<4;r++){
                if (OUT_BF16) ((u16*)Cp)[(row + r) * (size_t)N + col] = f2bf(acc[i][j][r]);
                else          ((float*)Cp)[(row + r) * (size_t)N + col] = acc[i][j][r];
            }
        }
}

// ---------------- RoPE (in-place on QKV) + V transpose ----------------
__global__ __launch_bounds__(256) void rope_kernel(u16* __restrict__ qkv,
                                                   const int* __restrict__ pos_ids,
                                                   u16* __restrict__ Vt){
    int idx = blockIdx.x * 256 + threadIdx.x;
    if (idx < 8388608){
        int tok = idx >> 11;
        int rem = idx & 2047;
        int h = rem >> 6, d = rem & 63;
        size_t base = (size_t)tok * QKVN + h * 128 + d;
        float v1 = bf2f(qkv[base]), v2 = bf2f(qkv[base + 64]);
        float p = (float)pos_ids[tok];
        float invf = exp2f((float)d * -0.2076205059304601f);  // 10000^(-d/64)
        float fr = p * invf;
        float s, c; sincosf(fr, &s, &c);
        qkv[base]      = f2bf(v1 * c - v2 * s);
        qkv[base + 64] = f2bf(v2 * c + v1 * s);
    } else if (idx < 10485760){
        int i2 = idx - 8388608;
        int tok = i2 >> 9;
        int rem = i2 & 511;
        int kv = rem >> 6, d = rem & 63;
        size_t base = (size_t)tok * QKVN + HIDDEN + kv * 128 + d;
        float v1 = bf2f(qkv[base]), v2 = bf2f(qkv[base + 64]);
        float p = (float)pos_ids[tok];
        float invf = exp2f((float)d * -0.2076205059304601f);
        float fr = p * invf;
        float s, c; sincosf(fr, &s, &c);
        qkv[base]      = f2bf(v1 * c - v2 * s);
        qkv[base + 64] = f2bf(v2 * c + v1 * s);
    } else if (idx < 14680064){
        int i3 = idx - 10485760;
        int tok = i3 >> 10;
        int rem = i3 & 1023;
        int kv = rem >> 7, d = rem & 127;
        int b = tok >> 11, s = tok & 2047;
        Vt[(((size_t)(b * NKV + kv)) * HD + d) * SEQL + s] =
            qkv[(size_t)tok * QKVN + 5120 + kv * 128 + d];
    }
}

// ---------------- Flash attention v3: LDS-staged, padded, load-balanced ----------------
// One block per (b, h, 64-row q tile). qt descending so long blocks dispatch first.
__global__ __launch_bounds__(256) void attn_kernel(const u16* __restrict__ qkv,
                                                   const u16* __restrict__ Vt,
                                                   u16* __restrict__ outb){
    __shared__ __align__(16) u16 Qs[64*QKS];
    __shared__ __align__(16) u16 Ks[64*QKS];
    __shared__ __align__(16) u16 Vs[128*VSS];      // [dim][key], padded
    __shared__ __align__(16) u16 Ps[4][16*QKS];

    int qt = 31 - (blockIdx.x >> 6);     // longest blocks first
    int bh = blockIdx.x & 63;
    int h  = bh & 31;
    int b  = bh >> 5;
    int kvh = h >> 2;                    // groups = 4
    int tid = threadIdx.x, wave = tid >> 6, lane = tid & 63;
    int quad = lane >> 4, l16 = lane & 15;
    int q0 = qt * 64;

    const u16* Qg  = qkv + (size_t)(b * SEQL + q0) * QKVN + h * HD;
    const u16* Kg0 = qkv + (size_t)(b * SEQL) * QKVN + HIDDEN + kvh * HD;
    const u16* Vg  = Vt + ((size_t)(b * NKV + kvh)) * HD * SEQL;
    u16* Pw = &Ps[wave][0];

    for (int i = tid; i < 1024; i += 256){
        int r = i >> 4, c = i & 15;
        *(uint4*)(Qs + r * QKS + c * 8) = *(const uint4*)(Qg + (size_t)r * QKVN + c * 8);
    }

    float m_i[4] = {-INFINITY, -INFINITY, -INFINITY, -INFINITY};
    float l_i[4] = {0.f, 0.f, 0.f, 0.f};
    f32x4 Oacc[8];
    #pragma unroll
    for (int t=0;t<8;t++) Oacc[t] = zero4();

    const float scale = 0.08838834764831845f;  // 1/sqrt(128)
    int kend = q0 + 64;
    for (int k0 = 0; k0 < kend; k0 += 64){
        __syncthreads();
        const u16* Kg = Kg0 + (size_t)k0 * QKVN;
        for (int i = tid; i < 1024; i += 256){
            int r = i >> 4, c = i & 15;
            *(uint4*)(Ks + r * QKS + c * 8) = *(const uint4*)(Kg + (size_t)r * QKVN + c * 8);
        }
        for (int i = tid; i < 1024; i += 256){
            int d = i >> 3, c = i & 7;
            *(uint4*)(Vs + d * VSS + c * 8) = *(const uint4*)(Vg + (size_t)d * SEQL + k0 + c * 8);
        }
        __syncthreads();

        // S strip (16 rows per wave x 64 cols)
        f32x4 st[4];
        #pragma unroll
        for (int t=0;t<4;t++) st[t] = zero4();
        #pragma unroll
        for (int kk = 0; kk < 128; kk += 32){
            bf16x8 aq = *(const bf16x8*)(Qs + (wave*16 + l16)*QKS + kk + quad*8);
            #pragma unroll
            for (int t=0;t<4;t++){
                bf16x8 bk = *(const bf16x8*)(Ks + (t*16 + l16)*QKS + kk + quad*8);
                st[t] = __builtin_amdgcn_mfma_f32_16x16x32_bf16(aq, bk, st[t], 0, 0, 0);
            }
        }

        // online softmax per row (C layout: row = quad*4+r, col = t*16+l16)
        bool needmask = (k0 + 63 >= q0 + wave*16);   // wave-uniform
        int row_g = q0 + wave*16 + quad*4;
        float alpha[4];
        #pragma unroll
        for (int r=0;r<4;r++){
            float mx = m_i[r];
            #pragma unroll
            for (int t=0;t<4;t++){
                float v = st[t][r] * scale;
                if (needmask){
                    int col = k0 + t*16 + l16;
                    v = (col <= row_g + r) ? v : -INFINITY;
                }
                st[t][r] = v;
                mx = fmaxf(mx, v);
            }
            #pragma unroll
            for (int m=8;m>=1;m>>=1) mx = fmaxf(mx, __shfl_xor(mx, m));
            float mnew = mx;
            alpha[r] = __expf(m_i[r] - mnew);
            float rs = 0.f;
            #pragma unroll
            for (int t=0;t<4;t++){
                float pv = __expf(st[t][r] - mnew);
                st[t][r] = pv;
                rs += pv;
            }
            #pragma unroll
            for (int m=8;m>=1;m>>=1) rs += __shfl_xor(rs, m);
            l_i[r] = l_i[r] * alpha[r] + rs;
            m_i[r] = mnew;
        }

        // rescale O
        #pragma unroll
        for (int t=0;t<8;t++)
            #pragma unroll
            for (int r=0;r<4;r++) Oacc[t][r] *= alpha[r];

        // P: C-layout -> per-wave LDS -> A-layout (wave-private, no barrier)
        #pragma unroll
        for (int t=0;t<4;t++)
            #pragma unroll
            for (int r=0;r<4;r++)
                Pw[(quad*4 + r)*QKS + t*16 + l16] = f2bf(st[t][r]);

        // O += P(16x64) @ V(64x128); Vs is [dim][key] padded
        #pragma unroll
        for (int kk = 0; kk < 64; kk += 32){
            bf16x8 ap = *(const bf16x8*)(Pw + l16*QKS + kk + quad*8);
            #pragma unroll
            for (int t=0;t<8;t++){
                bf16x8 bv = *(const bf16x8*)(Vs + (t*16 + l16)*VSS + kk + quad*8);
                Oacc[t] = __builtin_amdgcn_mfma_f32_16x16x32_bf16(ap, bv, Oacc[t], 0, 0, 0);
            }
        }
    }

    float invl[4];
    #pragma unroll
    for (int r=0;r<4;r++) invl[r] = 1.f / l_i[r];
    int row0 = q0 + wave*16 + quad*4;
    #pragma unroll
    for (int t=0;t<8;t++)
        #pragma unroll
        for (int r=0;r<4;r++){
            size_t o = ((size_t)(b * SEQL + row0 + r)) * HIDDEN + h * HD + t*16 + l16;
            outb[o] = f2bf(Oacc[t][r] * invl[r]);
        }
}

extern "C" void kernel_launch(void* const* d_in, const int* in_sizes, int n_in,
                              void* d_out, int out_size, void* d_ws, size_t ws_size,
                              hipStream_t stream){
    (void)in_sizes; (void)n_in; (void)out_size; (void)ws_size;
    const float* hs  = (const float*)d_in[0];
    const int*   pos = (const int*)d_in[1];
    const float* Wq  = (const float*)d_in[2];
    const float* Wk  = (const float*)d_in[3];
    const float* Wv  = (const float*)d_in[4];
    const float* Wo  = (const float*)d_in[5];
    float* out = (float*)d_out;
    char* ws = (char*)d_ws;

    u16* Xbf  = (u16*)(ws);              // 4096x4096 bf16 ; later reused as attn output
    u16* Wqkv = (u16*)(ws + 33554432);   // 6144x4096 bf16
    u16* Wob  = (u16*)(ws + 83886080);   // 4096x4096 bf16
    u16* QKVb = (u16*)(ws + 117440512);  // 4096x6144 bf16
    u16* Vt   = (u16*)(ws + 167772160);  // [2][8][128][2048] bf16
    u16* attn_bf = Xbf;

    cvt_kernel<<<16384, 256, 0, stream>>>(hs, Xbf, 4194304);
    cvt_kernel<<<16384, 256, 0, stream>>>(Wq, Wqkv, 4194304);
    cvt_kernel<<<4096,  256, 0, stream>>>(Wk, Wqkv + (size_t)4096*4096, 1048576);
    cvt_kernel<<<4096,  256, 0, stream>>>(Wv, Wqkv + (size_t)5120*4096, 1048576);
    cvt_kernel<<<16384, 256, 0, stream>>>(Wo, Wob, 4194304);

    gemm_bt<1><<<dim3(48, 32), 256, 0, stream>>>(Xbf, Wqkv, QKVb, NTOK, QKVN, HIDDEN);
    rope_kernel<<<57344, 256, 0, stream>>>(QKVb, pos, Vt);
    attn_kernel<<<BATCH*NH*(SEQL/64), 256, 0, stream>>>(QKVb, Vt, attn_bf);
    gemm_bt<0><<<dim3(32, 32), 256, 0, stream>>>(attn_bf, Wob, out, NTOK, HIDDEN, HIDDEN);
}

// Round 4
// 928.252 us; speedup vs baseline: 1.8649x; 1.1192x over previous
//
#include <hip/hip_runtime.h>
#include <cstdint>
#include <cstddef>

typedef unsigned short u16;
typedef short bf16x8 __attribute__((ext_vector_type(8)));
typedef float f32x4 __attribute__((ext_vector_type(4)));

#define HIDDEN 4096
#define NH 32
#define NKV 8
#define HD 128
#define SEQL 2048
#define BATCH 2
#define NTOK (BATCH*SEQL)          /* 4096 tokens */
#define QKVN (HIDDEN + 2*NKV*HD)   /* 6144 */

#define QKS 136   /* padded LDS row stride (u16) for Ps */

__device__ __forceinline__ u16 f2bf(float f){
    unsigned u = __float_as_uint(f);
    u += 0x7FFF + ((u >> 16) & 1);   // RNE
    return (u16)(u >> 16);
}
__device__ __forceinline__ float bf2f(u16 h){
    return __uint_as_float(((unsigned)h) << 16);
}
__device__ __forceinline__ f32x4 zero4(){
    f32x4 z; z[0]=0.f; z[1]=0.f; z[2]=0.f; z[3]=0.f; return z;
}

typedef const unsigned int __attribute__((address_space(1)))* gas1_t;
typedef unsigned int __attribute__((address_space(3)))* las3_t;
__device__ __forceinline__ void gload_lds16(const u16* g, u16* l){
    __builtin_amdgcn_global_load_lds((gas1_t)g, (las3_t)l, 16, 0, 0);
}

// ---------------- f32 -> bf16 conversion (vectorized x4) ----------------
__global__ __launch_bounds__(256) void cvt_kernel(const float* __restrict__ src,
                                                  u16* __restrict__ dst, int n4){
    int i = blockIdx.x * 256 + threadIdx.x;
    if (i < n4){
        float4 v = ((const float4*)src)[i];
        ushort4 o;
        o.x = f2bf(v.x); o.y = f2bf(v.y); o.z = f2bf(v.z); o.w = f2bf(v.w);
        ((ushort4*)dst)[i] = o;
    }
}

// ---------------- GEMM: C[m,n] = sum_k A[m,k]*B[n,k], A,B bf16 K-contig ----------------
template<int OUT_BF16>
__global__ __launch_bounds__(256) void gemm_bt(const u16* __restrict__ A,
                                               const u16* __restrict__ B,
                                               void* __restrict__ Cp,
                                               int M, int N, int K){
    __shared__ __align__(16) u16 As[128*32];
    __shared__ __align__(16) u16 Bs[128*32];
    int tid = threadIdx.x;
    int wave = tid >> 6, lane = tid & 63, quad = lane >> 4, l16 = lane & 15;
    int wm = wave & 1, wn = wave >> 1;
    size_t row0 = (size_t)blockIdx.y * 128, col0 = (size_t)blockIdx.x * 128;

    f32x4 acc[4][4];
    #pragma unroll
    for (int i=0;i<4;i++)
        #pragma unroll
        for (int j=0;j<4;j++) acc[i][j] = zero4();

    const u16* Ag = A + (row0 + (tid >> 2)) * (size_t)K + (tid & 3) * 8;
    const u16* Bg = B + (col0 + (tid >> 2)) * (size_t)K + (tid & 3) * 8;
    u16* Asp = As + tid * 8;
    u16* Bsp = Bs + tid * 8;
    size_t skip = (size_t)64 * K;

    for (int k0 = 0; k0 < K; k0 += 32){
        gload_lds16(Ag + k0,        Asp);
        gload_lds16(Ag + k0 + skip, Asp + 2048);
        gload_lds16(Bg + k0,        Bsp);
        gload_lds16(Bg + k0 + skip, Bsp + 2048);
        __syncthreads();
        bf16x8 af[4], bfr[4];
        #pragma unroll
        for (int i=0;i<4;i++) af[i]  = *(const bf16x8*)(As + (wm*64 + i*16 + l16)*32 + quad*8);
        #pragma unroll
        for (int j=0;j<4;j++) bfr[j] = *(const bf16x8*)(Bs + (wn*64 + j*16 + l16)*32 + quad*8);
        #pragma unroll
        for (int i=0;i<4;i++)
            #pragma unroll
            for (int j=0;j<4;j++)
                acc[i][j] = __builtin_amdgcn_mfma_f32_16x16x32_bf16(af[i], bfr[j], acc[i][j], 0, 0, 0);
        __syncthreads();
    }

    #pragma unroll
    for (int i=0;i<4;i++)
        #pragma unroll
        for (int j=0;j<4;j++){
            size_t row = row0 + wm*64 + i*16 + quad*4;
            size_t col = col0 + wn*64 + j*16 + l16;
            #pragma unroll
            for (int r=0;r<4;r++){
                if (OUT_BF16) ((u16*)Cp)[(row + r) * (size_t)N + col] = f2bf(acc[i][j][r]);
                else          ((float*)Cp)[(row + r) * (size_t)N + col] = acc[i][j][r];
            }
        }
}

// ---------------- RoPE (in-place on QKV, Q+K regions only) ----------------
__global__ __launch_bounds__(256) void rope_kernel(u16* __restrict__ qkv,
                                                   const int* __restrict__ pos_ids){
    int idx = blockIdx.x * 256 + threadIdx.x;
    if (idx < 8388608){
        int tok = idx >> 11;
        int rem = idx & 2047;
        int h = rem >> 6, d = rem & 63;
        size_t base = (size_t)tok * QKVN + h * 128 + d;
        float v1 = bf2f(qkv[base]), v2 = bf2f(qkv[base + 64]);
        float p = (float)pos_ids[tok];
        float invf = exp2f((float)d * -0.2076205059304601f);  // 10000^(-d/64)
        float fr = p * invf;
        float s, c; __sincosf(fr, &s, &c);
        qkv[base]      = f2bf(v1 * c - v2 * s);
        qkv[base + 64] = f2bf(v2 * c + v1 * s);
    } else {
        int i2 = idx - 8388608;
        int tok = i2 >> 9;
        int rem = i2 & 511;
        int kv = rem >> 6, d = rem & 63;
        size_t base = (size_t)tok * QKVN + HIDDEN + kv * 128 + d;
        float v1 = bf2f(qkv[base]), v2 = bf2f(qkv[base + 64]);
        float p = (float)pos_ids[tok];
        float invf = exp2f((float)d * -0.2076205059304601f);
        float fr = p * invf;
        float s, c; __sincosf(fr, &s, &c);
        qkv[base]      = f2bf(v1 * c - v2 * s);
        qkv[base + 64] = f2bf(v2 * c + v1 * s);
    }
}

// ---------------- V transpose: [tok][kv][d] -> Vt[b,kv][d][tok] ----------------
// Gather 8 strided u16 (L1-resident lines), write one coalesced uint4 per iter.
__global__ __launch_bounds__(256) void vtrans_kernel(const u16* __restrict__ qkv,
                                                     u16* __restrict__ Vt){
    int blk = blockIdx.x;            // 512 blocks: (b,kv) x 32 token tiles
    int tt = blk & 31, bkv = blk >> 5;
    int b = bkv >> 3, kv = bkv & 7;
    const u16* src = qkv + (size_t)(b * SEQL + tt * 64) * QKVN + 5120 + kv * HD;
    u16* dst = Vt + ((size_t)(b * NKV + kv)) * HD * SEQL + tt * 64;
    int tid = threadIdx.x;
    for (int i = tid; i < 1024; i += 256){
        int d = i >> 3, sc = i & 7;
        u16 tmp[8];
        #pragma unroll
        for (int j = 0; j < 8; j++) tmp[j] = src[(size_t)(sc * 8 + j) * QKVN + d];
        *(uint4*)(dst + (size_t)d * SEQL + sc * 8) = *(const uint4*)tmp;
    }
}

// ---------------- Flash attention v4: DMA-staged K/V w/ XOR swizzle, Q in regs ----------------
// LDS 49KB -> 3 blocks/CU. K LDS packed rows of 128 u16, chunk slot = c ^ (row&15).
// V LDS packed rows ([dim][64 keys]), chunk slot = c ^ (dim&7). Swizzle applied on the
// DMA *source* address so the packed destination is global_load_lds-compatible.
__global__ __launch_bounds__(256) void attn_kernel(const u16* __restrict__ qkv,
                                                   const u16* __restrict__ Vt,
                                                   u16* __restrict__ outb){
    __shared__ __align__(16) u16 Ks[64*128];
    __shared__ __align__(16) u16 Vs[128*64];
    __shared__ __align__(16) u16 Ps[4][16*QKS];

    int qt = 31 - (blockIdx.x >> 6);     // longest blocks first
    int bh = blockIdx.x & 63;
    int h  = bh & 31;
    int b  = bh >> 5;
    int kvh = h >> 2;
    int tid = threadIdx.x, wave = tid >> 6, lane = tid & 63;
    int quad = lane >> 4, l16 = lane & 15;
    int q0 = qt * 64, qrow = q0 + wave * 16;

    const u16* Qg  = qkv + (size_t)(b * SEQL + qrow + l16) * QKVN + h * HD;
    const u16* Kg0 = qkv + (size_t)(b * SEQL) * QKVN + HIDDEN + kvh * HD;
    const u16* Vg  = Vt + ((size_t)(b * NKV + kvh)) * HD * SEQL;
    u16* Pw = &Ps[wave][0];

    // Q fragments, pre-scaled by 1/sqrt(d), resident for the whole k-loop
    const float scale = 0.08838834764831845f;
    bf16x8 qf[4];
    #pragma unroll
    for (int c = 0; c < 4; c++){
        bf16x8 q = *(const bf16x8*)(Qg + c * 32 + quad * 8);
        #pragma unroll
        for (int e = 0; e < 8; e++){
            float f = bf2f((u16)q[e]) * scale;
            q[e] = (short)f2bf(f);
        }
        qf[c] = q;
    }

    // DMA staging addresses (per-lane, fixed across tiles)
    const u16* kg[4]; u16* kd[4];
    const u16* vg[4]; u16* vd[4];
    {
        int r4 = lane >> 4, s16 = lane & 15;
        int r8 = lane >> 3, s8 = lane & 7;
        #pragma unroll
        for (int i = 0; i < 4; i++){
            int lr = wave * 16 + i * 4 + r4;          // K local row 0..63
            int cK = s16 ^ (lr & 15);
            kg[i] = Kg0 + (size_t)lr * QKVN + cK * 8;
            kd[i] = Ks + lr * 128 + s16 * 8;          // = base + lane*16B
            int dr = wave * 32 + i * 8 + r8;          // V dim row 0..127
            int cV = s8 ^ (dr & 7);
            vg[i] = Vg + (size_t)dr * SEQL + cV * 8;
            vd[i] = Vs + dr * 64 + s8 * 8;            // = base + lane*16B
        }
    }

    float m_i[4] = {-INFINITY, -INFINITY, -INFINITY, -INFINITY};
    float l_i[4] = {0.f, 0.f, 0.f, 0.f};
    f32x4 Oacc[8];
    #pragma unroll
    for (int t=0;t<8;t++) Oacc[t] = zero4();

    int kend = q0 + 64;
    size_t kOffK = 0;
    for (int k0 = 0; k0 < kend; k0 += 64, kOffK += (size_t)64 * QKVN){
        __syncthreads();
        #pragma unroll
        for (int i = 0; i < 4; i++) gload_lds16(kg[i] + kOffK, kd[i]);
        #pragma unroll
        for (int i = 0; i < 4; i++) gload_lds16(vg[i] + k0, vd[i]);
        __syncthreads();

        // S strip (16 rows per wave x 64 keys), K read back through the swizzle
        f32x4 st[4];
        #pragma unroll
        for (int t=0;t<4;t++) st[t] = zero4();
        #pragma unroll
        for (int c4 = 0; c4 < 4; c4++){
            int cw = c4 * 4 + quad;
            #pragma unroll
            for (int t = 0; t < 4; t++){
                bf16x8 bk = *(const bf16x8*)(Ks + (t*16 + l16)*128 + (cw ^ l16)*8);
                st[t] = __builtin_amdgcn_mfma_f32_16x16x32_bf16(qf[c4], bk, st[t], 0, 0, 0);
            }
        }

        // online softmax (Q pre-scaled; C layout: row = quad*4+r, col = t*16+l16)
        bool needmask = (k0 + 63 >= qrow);   // wave-uniform
        int row_g = qrow + quad * 4;
        float alpha[4];
        #pragma unroll
        for (int r=0;r<4;r++){
            float mx = m_i[r];
            #pragma unroll
            for (int t=0;t<4;t++){
                float v = st[t][r];
                if (needmask){
                    int col = k0 + t*16 + l16;
                    v = (col <= row_g + r) ? v : -INFINITY;
                }
                st[t][r] = v;
                mx = fmaxf(mx, v);
            }
            #pragma unroll
            for (int m=8;m>=1;m>>=1) mx = fmaxf(mx, __shfl_xor(mx, m));
            float mnew = mx;
            alpha[r] = __expf(m_i[r] - mnew);
            float rs = 0.f;
            #pragma unroll
            for (int t=0;t<4;t++){
                float pv = __expf(st[t][r] - mnew);
                st[t][r] = pv;
                rs += pv;
            }
            #pragma unroll
            for (int m=8;m>=1;m>>=1) rs += __shfl_xor(rs, m);
            l_i[r] = l_i[r] * alpha[r] + rs;
            m_i[r] = mnew;
        }

        // rescale O
        #pragma unroll
        for (int t=0;t<8;t++)
            #pragma unroll
            for (int r=0;r<4;r++) Oacc[t][r] *= alpha[r];

        // P: C-layout -> per-wave LDS -> A-layout (wave-private, no barrier)
        #pragma unroll
        for (int t=0;t<4;t++)
            #pragma unroll
            for (int r=0;r<4;r++)
                Pw[(quad*4 + r)*QKS + t*16 + l16] = f2bf(st[t][r]);

        // O += P(16x64) @ V(64x128), V read back through the swizzle
        #pragma unroll
        for (int c2 = 0; c2 < 2; c2++){
            bf16x8 ap = *(const bf16x8*)(Pw + l16*QKS + c2*32 + quad*8);
            int cw = c2 * 4 + quad;
            #pragma unroll
            for (int t = 0; t < 8; t++){
                int d = t*16 + l16;
                bf16x8 bv = *(const bf16x8*)(Vs + d*64 + (cw ^ (l16 & 7))*8);
                Oacc[t] = __builtin_amdgcn_mfma_f32_16x16x32_bf16(ap, bv, Oacc[t], 0, 0, 0);
            }
        }
    }

    float invl[4];
    #pragma unroll
    for (int r=0;r<4;r++) invl[r] = 1.f / l_i[r];
    int row0 = qrow + quad * 4;
    #pragma unroll
    for (int t=0;t<8;t++)
        #pragma unroll
        for (int r=0;r<4;r++){
            size_t o = ((size_t)(b * SEQL + row0 + r)) * HIDDEN + h * HD + t*16 + l16;
            outb[o] = f2bf(Oacc[t][r] * invl[r]);
        }
}

extern "C" void kernel_launch(void* const* d_in, const int* in_sizes, int n_in,
                              void* d_out, int out_size, void* d_ws, size_t ws_size,
                              hipStream_t stream){
    (void)in_sizes; (void)n_in; (void)out_size; (void)ws_size;
    const float* hs  = (const float*)d_in[0];
    const int*   pos = (const int*)d_in[1];
    const float* Wq  = (const float*)d_in[2];
    const float* Wk  = (const float*)d_in[3];
    const float* Wv  = (const float*)d_in[4];
    const float* Wo  = (const float*)d_in[5];
    float* out = (float*)d_out;
    char* ws = (char*)d_ws;

    u16* Xbf  = (u16*)(ws);              // 4096x4096 bf16 ; later reused as attn output
    u16* Wqkv = (u16*)(ws + 33554432);   // 6144x4096 bf16
    u16* Wob  = (u16*)(ws + 83886080);   // 4096x4096 bf16
    u16* QKVb = (u16*)(ws + 117440512);  // 4096x6144 bf16
    u16* Vt   = (u16*)(ws + 167772160);  // [2][8][128][2048] bf16
    u16* attn_bf = Xbf;

    cvt_kernel<<<16384, 256, 0, stream>>>(hs, Xbf, 4194304);
    cvt_kernel<<<16384, 256, 0, stream>>>(Wq, Wqkv, 4194304);
    cvt_kernel<<<4096,  256, 0, stream>>>(Wk, Wqkv + (size_t)4096*4096, 1048576);
    cvt_kernel<<<4096,  256, 0, stream>>>(Wv, Wqkv + (size_t)5120*4096, 1048576);
    cvt_kernel<<<16384, 256, 0, stream>>>(Wo, Wob, 4194304);

    gemm_bt<1><<<dim3(48, 32), 256, 0, stream>>>(Xbf, Wqkv, QKVb, NTOK, QKVN, HIDDEN);
    rope_kernel<<<40960, 256, 0, stream>>>(QKVb, pos);
    vtrans_kernel<<<512, 256, 0, stream>>>(QKVb, Vt);
    attn_kernel<<<BATCH*NH*(SEQL/64), 256, 0, stream>>>(QKVb, Vt, attn_bf);
    gemm_bt<0><<<dim3(32, 32), 256, 0, stream>>>(attn_bf, Wob, out, NTOK, HIDDEN, HIDDEN);
}

// Round 5
// 921.283 us; speedup vs baseline: 1.8791x; 1.0076x over previous
//
#include <hip/hip_runtime.h>
#include <cstdint>
#include <cstddef>

typedef unsigned short u16;
typedef short bf16x8 __attribute__((ext_vector_type(8)));
typedef float f32x4 __attribute__((ext_vector_type(4)));

#define HIDDEN 4096
#define NH 32
#define NKV 8
#define HD 128
#define SEQL 2048
#define BATCH 2
#define NTOK (BATCH*SEQL)          /* 4096 tokens */
#define QKVN (HIDDEN + 2*NKV*HD)   /* 6144 */

#define QKS 136   /* padded LDS row stride (u16) for Ps */

__device__ __forceinline__ u16 f2bf(float f){
    unsigned u = __float_as_uint(f);
    u += 0x7FFF + ((u >> 16) & 1);   // RNE
    return (u16)(u >> 16);
}
__device__ __forceinline__ float bf2f(u16 h){
    return __uint_as_float(((unsigned)h) << 16);
}
__device__ __forceinline__ f32x4 zero4(){
    f32x4 z; z[0]=0.f; z[1]=0.f; z[2]=0.f; z[3]=0.f; return z;
}

typedef const unsigned int __attribute__((address_space(1)))* gas1_t;
typedef unsigned int __attribute__((address_space(3)))* las3_t;
__device__ __forceinline__ void gload_lds16(const u16* g, u16* l){
    __builtin_amdgcn_global_load_lds((gas1_t)g, (las3_t)l, 16, 0, 0);
}

// ---------------- f32 -> bf16 conversion (vectorized x4) ----------------
__global__ __launch_bounds__(256) void cvt_kernel(const float* __restrict__ src,
                                                  u16* __restrict__ dst, int n4){
    int i = blockIdx.x * 256 + threadIdx.x;
    if (i < n4){
        float4 v = ((const float4*)src)[i];
        ushort4 o;
        o.x = f2bf(v.x); o.y = f2bf(v.y); o.z = f2bf(v.z); o.w = f2bf(v.w);
        ((ushort4*)dst)[i] = o;
    }
}

// ---------------- GEMM: C[m,n] = sum_k A[m,k]*B[n,k], A,B bf16 K-contig ----------------
// 128x128 tile, BK=32, DMA staging. LDS uses an XOR chunk swizzle (packed, DMA-compatible):
// row r, 16B-chunk c stored in 2-row group g=r>>1 at slot ((r&1)*4+c)^(g&7).
// Fragment reads then alias banks only 2-way (free) instead of 8-way.
template<int OUT_BF16>
__global__ __launch_bounds__(256) void gemm_bt(const u16* __restrict__ A,
                                               const u16* __restrict__ B,
                                               void* __restrict__ Cp,
                                               int M, int N, int K){
    __shared__ __align__(16) u16 As[128*32];
    __shared__ __align__(16) u16 Bs[128*32];
    int tid = threadIdx.x;
    int wave = tid >> 6, lane = tid & 63, quad = lane >> 4, l16 = lane & 15;
    int wm = wave & 1, wn = wave >> 1;
    size_t row0 = (size_t)blockIdx.y * 128, col0 = (size_t)blockIdx.x * 128;

    f32x4 acc[4][4];
    #pragma unroll
    for (int i=0;i<4;i++)
        #pragma unroll
        for (int j=0;j<4;j++) acc[i][j] = zero4();

    // staging: thread tid fills dest chunks tid and tid+256 (dest = base + lane*16B).
    // source chunk for dest (g = tid>>3, s = tid&7): cc = s^(g&7), r = 2g+(cc>>2), c = cc&3.
    int sg = tid >> 3, ss = tid & 7;
    int scc = ss ^ (sg & 7);
    int sr = sg * 2 + (scc >> 2), sc = scc & 3;
    const u16* Ag = A + (row0 + sr) * (size_t)K + sc * 8;
    const u16* Bg = B + (col0 + sr) * (size_t)K + sc * 8;
    u16* Asp = As + tid * 8;
    u16* Bsp = Bs + tid * 8;
    size_t skip = (size_t)64 * K;   // second half: same (g&7) => same swizzle, row +64

    // fragment read offsets: row rr = w*64 + i*16 + l16 -> g = w*32+i*8+(l16>>1),
    // slot s = ((l16&1)*4+quad)^((l16>>1)&7) (per-thread constant), off = g*64+s*8.
    int fs = (((l16 & 1) * 4 + quad) ^ ((l16 >> 1) & 7)) * 8;
    int aoff = wm * 2048 + (l16 >> 1) * 64 + fs;
    int boff = wn * 2048 + (l16 >> 1) * 64 + fs;

    for (int k0 = 0; k0 < K; k0 += 32){
        gload_lds16(Ag + k0,        Asp);
        gload_lds16(Ag + k0 + skip, Asp + 2048);
        gload_lds16(Bg + k0,        Bsp);
        gload_lds16(Bg + k0 + skip, Bsp + 2048);
        __syncthreads();
        bf16x8 af[4], bfr[4];
        #pragma unroll
        for (int i=0;i<4;i++) af[i]  = *(const bf16x8*)(As + aoff + i*512);
        #pragma unroll
        for (int j=0;j<4;j++) bfr[j] = *(const bf16x8*)(Bs + boff + j*512);
        #pragma unroll
        for (int i=0;i<4;i++)
            #pragma unroll
            for (int j=0;j<4;j++)
                acc[i][j] = __builtin_amdgcn_mfma_f32_16x16x32_bf16(af[i], bfr[j], acc[i][j], 0, 0, 0);
        __syncthreads();
    }

    #pragma unroll
    for (int i=0;i<4;i++)
        #pragma unroll
        for (int j=0;j<4;j++){
            size_t row = row0 + wm*64 + i*16 + quad*4;
            size_t col = col0 + wn*64 + j*16 + l16;
            #pragma unroll
            for (int r=0;r<4;r++){
                if (OUT_BF16) ((u16*)Cp)[(row + r) * (size_t)N + col] = f2bf(acc[i][j][r]);
                else          ((float*)Cp)[(row + r) * (size_t)N + col] = acc[i][j][r];
            }
        }
}

// ---------------- RoPE (in-place on QKV, Q+K regions only) ----------------
__global__ __launch_bounds__(256) void rope_kernel(u16* __restrict__ qkv,
                                                   const int* __restrict__ pos_ids){
    int idx = blockIdx.x * 256 + threadIdx.x;
    if (idx < 8388608){
        int tok = idx >> 11;
        int rem = idx & 2047;
        int h = rem >> 6, d = rem & 63;
        size_t base = (size_t)tok * QKVN + h * 128 + d;
        float v1 = bf2f(qkv[base]), v2 = bf2f(qkv[base + 64]);
        float p = (float)pos_ids[tok];
        float invf = exp2f((float)d * -0.2076205059304601f);  // 10000^(-d/64)
        float fr = p * invf;
        float s, c; __sincosf(fr, &s, &c);
        qkv[base]      = f2bf(v1 * c - v2 * s);
        qkv[base + 64] = f2bf(v2 * c + v1 * s);
    } else {
        int i2 = idx - 8388608;
        int tok = i2 >> 9;
        int rem = i2 & 511;
        int kv = rem >> 6, d = rem & 63;
        size_t base = (size_t)tok * QKVN + HIDDEN + kv * 128 + d;
        float v1 = bf2f(qkv[base]), v2 = bf2f(qkv[base + 64]);
        float p = (float)pos_ids[tok];
        float invf = exp2f((float)d * -0.2076205059304601f);
        float fr = p * invf;
        float s, c; __sincosf(fr, &s, &c);
        qkv[base]      = f2bf(v1 * c - v2 * s);
        qkv[base + 64] = f2bf(v2 * c + v1 * s);
    }
}

// ---------------- V transpose: [tok][kv][d] -> Vt[b,kv][d][tok] ----------------
__global__ __launch_bounds__(256) void vtrans_kernel(const u16* __restrict__ qkv,
                                                     u16* __restrict__ Vt){
    int blk = blockIdx.x;            // 512 blocks: (b,kv) x 32 token tiles
    int tt = blk & 31, bkv = blk >> 5;
    int b = bkv >> 3, kv = bkv & 7;
    const u16* src = qkv + (size_t)(b * SEQL + tt * 64) * QKVN + 5120 + kv * HD;
    u16* dst = Vt + ((size_t)(b * NKV + kv)) * HD * SEQL + tt * 64;
    int tid = threadIdx.x;
    for (int i = tid; i < 1024; i += 256){
        int d = i >> 3, sc = i & 7;
        u16 tmp[8];
        #pragma unroll
        for (int j = 0; j < 8; j++) tmp[j] = src[(size_t)(sc * 8 + j) * QKVN + d];
        *(uint4*)(dst + (size_t)d * SEQL + sc * 8) = *(const uint4*)tmp;
    }
}

// ---------------- Flash attention v4: DMA-staged K/V w/ XOR swizzle, Q in regs ----------------
__global__ __launch_bounds__(256) void attn_kernel(const u16* __restrict__ qkv,
                                                   const u16* __restrict__ Vt,
                                                   u16* __restrict__ outb){
    __shared__ __align__(16) u16 Ks[64*128];
    __shared__ __align__(16) u16 Vs[128*64];
    __shared__ __align__(16) u16 Ps[4][16*QKS];

    int qt = 31 - (blockIdx.x >> 6);     // longest blocks first
    int bh = blockIdx.x & 63;
    int h  = bh & 31;
    int b  = bh >> 5;
    int kvh = h >> 2;
    int tid = threadIdx.x, wave = tid >> 6, lane = tid & 63;
    int quad = lane >> 4, l16 = lane & 15;
    int q0 = qt * 64, qrow = q0 + wave * 16;

    const u16* Qg  = qkv + (size_t)(b * SEQL + qrow + l16) * QKVN + h * HD;
    const u16* Kg0 = qkv + (size_t)(b * SEQL) * QKVN + HIDDEN + kvh * HD;
    const u16* Vg  = Vt + ((size_t)(b * NKV + kvh)) * HD * SEQL;
    u16* Pw = &Ps[wave][0];

    // Q fragments, pre-scaled by 1/sqrt(d), resident for the whole k-loop
    const float scale = 0.08838834764831845f;
    bf16x8 qf[4];
    #pragma unroll
    for (int c = 0; c < 4; c++){
        bf16x8 q = *(const bf16x8*)(Qg + c * 32 + quad * 8);
        #pragma unroll
        for (int e = 0; e < 8; e++){
            float f = bf2f((u16)q[e]) * scale;
            q[e] = (short)f2bf(f);
        }
        qf[c] = q;
    }

    // DMA staging addresses (per-lane, fixed across tiles)
    const u16* kg[4]; u16* kd[4];
    const u16* vg[4]; u16* vd[4];
    {
        int r4 = lane >> 4, s16 = lane & 15;
        int r8 = lane >> 3, s8 = lane & 7;
        #pragma unroll
        for (int i = 0; i < 4; i++){
            int lr = wave * 16 + i * 4 + r4;          // K local row 0..63
            int cK = s16 ^ (lr & 15);
            kg[i] = Kg0 + (size_t)lr * QKVN + cK * 8;
            kd[i] = Ks + lr * 128 + s16 * 8;          // = base + lane*16B
            int dr = wave * 32 + i * 8 + r8;          // V dim row 0..127
            int cV = s8 ^ (dr & 7);
            vg[i] = Vg + (size_t)dr * SEQL + cV * 8;
            vd[i] = Vs + dr * 64 + s8 * 8;            // = base + lane*16B
        }
    }

    float m_i[4] = {-INFINITY, -INFINITY, -INFINITY, -INFINITY};
    float l_i[4] = {0.f, 0.f, 0.f, 0.f};
    f32x4 Oacc[8];
    #pragma unroll
    for (int t=0;t<8;t++) Oacc[t] = zero4();

    int kend = q0 + 64;
    size_t kOffK = 0;
    for (int k0 = 0; k0 < kend; k0 += 64, kOffK += (size_t)64 * QKVN){
        __syncthreads();
        #pragma unroll
        for (int i = 0; i < 4; i++) gload_lds16(kg[i] + kOffK, kd[i]);
        #pragma unroll
        for (int i = 0; i < 4; i++) gload_lds16(vg[i] + k0, vd[i]);
        __syncthreads();

        // S strip (16 rows per wave x 64 keys), K read back through the swizzle
        f32x4 st[4];
        #pragma unroll
        for (int t=0;t<4;t++) st[t] = zero4();
        #pragma unroll
        for (int c4 = 0; c4 < 4; c4++){
            int cw = c4 * 4 + quad;
            #pragma unroll
            for (int t = 0; t < 4; t++){
                bf16x8 bk = *(const bf16x8*)(Ks + (t*16 + l16)*128 + (cw ^ l16)*8);
                st[t] = __builtin_amdgcn_mfma_f32_16x16x32_bf16(qf[c4], bk, st[t], 0, 0, 0);
            }
        }

        // online softmax (Q pre-scaled; C layout: row = quad*4+r, col = t*16+l16)
        bool needmask = (k0 + 63 >= qrow);   // wave-uniform
        int row_g = qrow + quad * 4;
        float alpha[4];
        #pragma unroll
        for (int r=0;r<4;r++){
            float mx = m_i[r];
            #pragma unroll
            for (int t=0;t<4;t++){
                float v = st[t][r];
                if (needmask){
                    int col = k0 + t*16 + l16;
                    v = (col <= row_g + r) ? v : -INFINITY;
                }
                st[t][r] = v;
                mx = fmaxf(mx, v);
            }
            #pragma unroll
            for (int m=8;m>=1;m>>=1) mx = fmaxf(mx, __shfl_xor(mx, m));
            float mnew = mx;
            alpha[r] = __expf(m_i[r] - mnew);
            float rs = 0.f;
            #pragma unroll
            for (int t=0;t<4;t++){
                float pv = __expf(st[t][r] - mnew);
                st[t][r] = pv;
                rs += pv;
            }
            #pragma unroll
            for (int m=8;m>=1;m>>=1) rs += __shfl_xor(rs, m);
            l_i[r] = l_i[r] * alpha[r] + rs;
            m_i[r] = mnew;
        }

        // rescale O
        #pragma unroll
        for (int t=0;t<8;t++)
            #pragma unroll
            for (int r=0;r<4;r++) Oacc[t][r] *= alpha[r];

        // P: C-layout -> per-wave LDS -> A-layout (wave-private, no barrier)
        #pragma unroll
        for (int t=0;t<4;t++)
            #pragma unroll
            for (int r=0;r<4;r++)
                Pw[(quad*4 + r)*QKS + t*16 + l16] = f2bf(st[t][r]);

        // O += P(16x64) @ V(64x128), V read back through the swizzle
        #pragma unroll
        for (int c2 = 0; c2 < 2; c2++){
            bf16x8 ap = *(const bf16x8*)(Pw + l16*QKS + c2*32 + quad*8);
            int cw = c2 * 4 + quad;
            #pragma unroll
            for (int t = 0; t < 8; t++){
                int d = t*16 + l16;
                bf16x8 bv = *(const bf16x8*)(Vs + d*64 + (cw ^ (l16 & 7))*8);
                Oacc[t] = __builtin_amdgcn_mfma_f32_16x16x32_bf16(ap, bv, Oacc[t], 0, 0, 0);
            }
        }
    }

    float invl[4];
    #pragma unroll
    for (int r=0;r<4;r++) invl[r] = 1.f / l_i[r];
    int row0 = qrow + quad * 4;
    #pragma unroll
    for (int t=0;t<8;t++)
        #pragma unroll
        for (int r=0;r<4;r++){
            size_t o = ((size_t)(b * SEQL + row0 + r)) * HIDDEN + h * HD + t*16 + l16;
            outb[o] = f2bf(Oacc[t][r] * invl[r]);
        }
}

extern "C" void kernel_launch(void* const* d_in, const int* in_sizes, int n_in,
                              void* d_out, int out_size, void* d_ws, size_t ws_size,
                              hipStream_t stream){
    (void)in_sizes; (void)n_in; (void)out_size; (void)ws_size;
    const float* hs  = (const float*)d_in[0];
    const int*   pos = (const int*)d_in[1];
    const float* Wq  = (const float*)d_in[2];
    const float* Wk  = (const float*)d_in[3];
    const float* Wv  = (const float*)d_in[4];
    const float* Wo  = (const float*)d_in[5];
    float* out = (float*)d_out;
    char* ws = (char*)d_ws;

    u16* Xbf  = (u16*)(ws);              // 4096x4096 bf16 ; later reused as attn output
    u16* Wqkv = (u16*)(ws + 33554432);   // 6144x4096 bf16
    u16* Wob  = (u16*)(ws + 83886080);   // 4096x4096 bf16
    u16* QKVb = (u16*)(ws + 117440512);  // 4096x6144 bf16
    u16* Vt   = (u16*)(ws + 167772160);  // [2][8][128][2048] bf16
    u16* attn_bf = Xbf;

    cvt_kernel<<<16384, 256, 0, stream>>>(hs, Xbf, 4194304);
    cvt_kernel<<<16384, 256, 0, stream>>>(Wq, Wqkv, 4194304);
    cvt_kernel<<<4096,  256, 0, stream>>>(Wk, Wqkv + (size_t)4096*4096, 1048576);
    cvt_kernel<<<4096,  256, 0, stream>>>(Wv, Wqkv + (size_t)5120*4096, 1048576);
    cvt_kernel<<<16384, 256, 0, stream>>>(Wo, Wob, 4194304);

    gemm_bt<1><<<dim3(48, 32), 256, 0, stream>>>(Xbf, Wqkv, QKVb, NTOK, QKVN, HIDDEN);
    rope_kernel<<<40960, 256, 0, stream>>>(QKVb, pos);
    vtrans_kernel<<<512, 256, 0, stream>>>(QKVb, Vt);
    attn_kernel<<<BATCH*NH*(SEQL/64), 256, 0, stream>>>(QKVb, Vt, attn_bf);
    gemm_bt<0><<<dim3(32, 32), 256, 0, stream>>>(attn_bf, Wob, out, NTOK, HIDDEN, HIDDEN);
}